// Round 7
// baseline (290.684 us; speedup 1.0000x reference)
//
#include <hip/hip_runtime.h>

// GCN_4492535792198: 3-layer GCN forward on MI355X (gfx950).
// N=50000, E=800000, D: 128->128->64. Outputs: logp[N,64], e1[N,128], e2[N,128], e3[N,64].
// R9 == R8 with staging-count fix: mfma_gemm_b_kernel's inline-W-transpose needs
//   DOUT/8 iterations (DOUT*32 float4 slots), not DOUT/16 — half of Ws was
//   uninitialized -> NaN. k1's W1 staging (16 iters) was already correct.
// R8: (a) fused fillslots + gemm1 (block-role split; gemm1 A from global, Ws-only
//   LDS); (b) prep kernel removed (inline W transpose per GEMM, per-wave dtype
//   detect in fill, cnt via hipMemsetAsync). 7 dispatches.

typedef __attribute__((ext_vector_type(8))) short short8;   // 8 x bf16 (4 VGPRs)
typedef __attribute__((ext_vector_type(4))) float f32x4;

#define SLOT_CAP 64
#define FILL_CHUNK 4096

__device__ __forceinline__ ushort f2bf(float f) {
    union { float f; unsigned u; } a; a.f = f;
    unsigned r = a.u + 0x7fffu + ((a.u >> 16) & 1u);   // RNE (finite data)
    return (ushort)(r >> 16);
}
__device__ __forceinline__ float bflo(unsigned u) { return __uint_as_float(u << 16); }
__device__ __forceinline__ float bfhi(unsigned u) { return __uint_as_float(u & 0xffff0000u); }

__device__ __forceinline__ int edge_at(const void* ei, int is64, long long i) {
    if (is64) return (int)((const long long*)ei)[i];
    return ((const int*)ei)[i];
}

__device__ __forceinline__ short8 pack_bf8(float4 a, float4 b) {
    short8 r;
    r[0] = (short)f2bf(a.x); r[1] = (short)f2bf(a.y);
    r[2] = (short)f2bf(a.z); r[3] = (short)f2bf(a.w);
    r[4] = (short)f2bf(b.x); r[5] = (short)f2bf(b.y);
    r[6] = (short)f2bf(b.z); r[7] = (short)f2bf(b.w);
    return r;
}

// ---------------- fused: XCD-partitioned slot fill + gemm1 (x @ W1 -> xw bf16) ----
__global__ __launch_bounds__(256) void k1_fill_gemm_kernel(
    const void* ei, int E, int nper, int* __restrict__ cnt, int* __restrict__ slots,
    const float* __restrict__ A, const float* __restrict__ W1,
    ushort* __restrict__ xw, int M, int nfill) {
    __shared__ ushort Ws[128 * 136];
    const int b = blockIdx.x;
    const int tid = threadIdx.x;

    if (b < nfill) {
        // ---- fill role ----
        const int lane = tid & 63;
        long long v64 = ((const long long*)ei)[lane];
        int bad = (v64 < 0 || v64 >= (1LL << 32)) ? 1 : 0;
        unsigned long long mm = __ballot(bad);
        const int is64 = (mm == 0ULL) ? 1 : 0;
        const int part = b & 7;
        const int lo = part * nper;
        const int hi = lo + nper;
        const int e0 = (b >> 3) * FILL_CHUNK;
        const int e1 = (e0 + FILL_CHUNK < E) ? e0 + FILL_CHUNK : E;
        for (int e = e0 + tid; e < e1; e += 256) {
            int d = edge_at(ei, is64, (long long)E + e);
            if (d >= lo && d < hi) {
                int s = edge_at(ei, is64, e);
                int p = atomicAdd(&cnt[d], 1);
                if (p < SLOT_CAP) slots[(d << 6) + p] = s;
            }
        }
        return;
    }

    // ---- gemm role ----
    const int r0 = (b - nfill) * 128;
    // stage Ws[n][k] = bf16(W1[k][n]); 4096 float4 slots over W1[128][128]
#pragma unroll
    for (int i = 0; i < 16; ++i) {
        int li = tid + i * 256;
        int k = li >> 5, n4 = li & 31;
        float4 v = ((const float4*)W1)[li];
        Ws[(n4 * 4 + 0) * 136 + k] = f2bf(v.x);
        Ws[(n4 * 4 + 1) * 136 + k] = f2bf(v.y);
        Ws[(n4 * 4 + 2) * 136 + k] = f2bf(v.z);
        Ws[(n4 * 4 + 3) * 136 + k] = f2bf(v.w);
    }
    __syncthreads();

    const int wid = tid >> 6;
    const int lane = tid & 63;
    const int m = lane & 15, quad = lane >> 4;
    const int row0 = r0 + wid * 32 + m;
    const int row1 = row0 + 16;
    const bool ok0 = row0 < M, ok1 = row1 < M;
    const float* a0p = A + (size_t)row0 * 128;
    const float* a1p = A + (size_t)row1 * 128;

    f32x4 acc[2][8];
#pragma unroll
    for (int rt = 0; rt < 2; ++rt)
#pragma unroll
        for (int nt = 0; nt < 8; ++nt) acc[rt][nt] = (f32x4){0.f, 0.f, 0.f, 0.f};

    const float4 z4 = make_float4(0.f, 0.f, 0.f, 0.f);
#pragma unroll
    for (int kt = 0; kt < 4; ++kt) {
        const int ko = kt * 32 + quad * 8;
        float4 fa0 = ok0 ? *(const float4*)(a0p + ko)     : z4;
        float4 fb0 = ok0 ? *(const float4*)(a0p + ko + 4) : z4;
        float4 fa1 = ok1 ? *(const float4*)(a1p + ko)     : z4;
        float4 fb1 = ok1 ? *(const float4*)(a1p + ko + 4) : z4;
        short8 af0 = pack_bf8(fa0, fb0);
        short8 af1 = pack_bf8(fa1, fb1);
        short8 bfr[8];
#pragma unroll
        for (int nt = 0; nt < 8; ++nt)
            bfr[nt] = *(const short8*)&Ws[(nt * 16 + m) * 136 + ko];
#pragma unroll
        for (int nt = 0; nt < 8; ++nt) {
            acc[0][nt] = __builtin_amdgcn_mfma_f32_16x16x32_bf16(af0, bfr[nt], acc[0][nt], 0, 0, 0);
            acc[1][nt] = __builtin_amdgcn_mfma_f32_16x16x32_bf16(af1, bfr[nt], acc[1][nt], 0, 0, 0);
        }
    }
#pragma unroll
    for (int rt = 0; rt < 2; ++rt)
#pragma unroll
        for (int nt = 0; nt < 8; ++nt)
#pragma unroll
            for (int i = 0; i < 4; ++i) {
                int row = r0 + wid * 32 + rt * 16 + quad * 4 + i;
                if (row < M) xw[(size_t)row * 128 + nt * 16 + m] = f2bf(acc[rt][nt][i]);
            }
}

// ---------------- MFMA GEMM (bf16 input, pre-relu'd): xw = A @ W, inline W transpose
template <int DOUT>
__global__ __launch_bounds__(256) void mfma_gemm_b_kernel(
    const ushort* __restrict__ A, const float* __restrict__ W,
    ushort* __restrict__ xw, int M) {
    constexpr int NT = DOUT / 16;
    __shared__ ushort As[128 * 136];
    __shared__ ushort Ws[DOUT * 136];
    const int tid = threadIdx.x;
    const int r0 = blockIdx.x * 128;
    const int wid = tid >> 6;
    const int lane = tid & 63;
    const int m = lane & 15, quad = lane >> 4;

#pragma unroll
    for (int i = 0; i < 8; ++i) {
        int li = tid + i * 256;             // 2048 uint4 slots (128 rows x 16)
        int row = li >> 4, c = li & 15;
        uint4 v = make_uint4(0u, 0u, 0u, 0u);
        int gr = r0 + row;
        if (gr < M) v = ((const uint4*)A)[(size_t)gr * 16 + c];
        *(uint4*)&As[row * 136 + c * 8] = v;
    }
    // stage Ws[n][k] = bf16(W[k][n]); W is [128][DOUT] fp32 -> DOUT*32 float4 slots
    // -> DOUT/8 iterations of 256 threads (FIXED: was DOUT/16, left half of Ws junk).
#pragma unroll
    for (int i = 0; i < DOUT / 8; ++i) {
        int li = tid + i * 256;
        int k = li / (DOUT / 4), n4 = li % (DOUT / 4);
        float4 v = ((const float4*)W)[li];
        Ws[(n4 * 4 + 0) * 136 + k] = f2bf(v.x);
        Ws[(n4 * 4 + 1) * 136 + k] = f2bf(v.y);
        Ws[(n4 * 4 + 2) * 136 + k] = f2bf(v.z);
        Ws[(n4 * 4 + 3) * 136 + k] = f2bf(v.w);
    }
    __syncthreads();

    f32x4 acc[2][NT];
#pragma unroll
    for (int rt = 0; rt < 2; ++rt)
#pragma unroll
        for (int nt = 0; nt < NT; ++nt) acc[rt][nt] = (f32x4){0.f, 0.f, 0.f, 0.f};

#pragma unroll
    for (int kt = 0; kt < 4; ++kt) {
        const int ko = kt * 32 + quad * 8;
        short8 af0 = *(const short8*)&As[(wid * 32 + m) * 136 + ko];
        short8 af1 = *(const short8*)&As[(wid * 32 + 16 + m) * 136 + ko];
        short8 bfr[NT];
#pragma unroll
        for (int nt = 0; nt < NT; ++nt)
            bfr[nt] = *(const short8*)&Ws[(nt * 16 + m) * 136 + ko];
#pragma unroll
        for (int nt = 0; nt < NT; ++nt) {
            acc[0][nt] = __builtin_amdgcn_mfma_f32_16x16x32_bf16(af0, bfr[nt], acc[0][nt], 0, 0, 0);
            acc[1][nt] = __builtin_amdgcn_mfma_f32_16x16x32_bf16(af1, bfr[nt], acc[1][nt], 0, 0, 0);
        }
    }
#pragma unroll
    for (int rt = 0; rt < 2; ++rt)
#pragma unroll
        for (int nt = 0; nt < NT; ++nt)
#pragma unroll
            for (int i = 0; i < 4; ++i) {
                int row = r0 + wid * 32 + rt * 16 + quad * 4 + i;
                if (row < M) xw[(size_t)row * DOUT + nt * 16 + m] = f2bf(acc[rt][nt][i]);
            }
}

// NOTE: parameter names must not collide with vector member names (.x/.y/.z/.w).
#define ACC8(W_, V_)                                               \
    acc[0] += W_ * bflo(V_.x); acc[1] += W_ * bfhi(V_.x);          \
    acc[2] += W_ * bflo(V_.y); acc[3] += W_ * bfhi(V_.y);          \
    acc[4] += W_ * bflo(V_.z); acc[5] += W_ * bfhi(V_.z);          \
    acc[6] += W_ * bflo(V_.w); acc[7] += W_ * bfhi(V_.w);

// ---------------- aggregation layers 1/2 (bf16 gather, slot-based, 8-deep) -------
__global__ __launch_bounds__(256) void agg12_kernel(
    const ushort* __restrict__ xw, const int* __restrict__ cnt,
    const int* __restrict__ slots, const float* __restrict__ bias,
    float* __restrict__ out, ushort* __restrict__ xwb, int n) {
    const int tid = threadIdx.x;
    const int node = blockIdx.x * 16 + (tid >> 4);
    const int j = tid & 15;
    if (node >= n) return;
    const uint4* xw4 = (const uint4*)xw;   // row pitch = 16 uint4
    const int degf = cnt[node];
    const int deg = (degf < SLOT_CAP) ? degf : SLOT_CAP;
    const float di = rsqrtf((float)(degf + 1));
    const int base = node << 6;
    float acc[8];
#pragma unroll
    for (int i = 0; i < 8; ++i) acc[i] = 0.f;

    int p = 0;
    while (p + 8 <= deg) {
        const int4 ca = *(const int4*)&slots[base + p];
        const int4 cb = *(const int4*)&slots[base + p + 4];
        const int g0 = cnt[ca.x], g1 = cnt[ca.y], g2 = cnt[ca.z], g3 = cnt[ca.w];
        const int g4 = cnt[cb.x], g5 = cnt[cb.y], g6 = cnt[cb.z], g7 = cnt[cb.w];
        uint4 v0 = xw4[(size_t)ca.x * 16 + j];
        uint4 v1 = xw4[(size_t)ca.y * 16 + j];
        uint4 v2 = xw4[(size_t)ca.z * 16 + j];
        uint4 v3 = xw4[(size_t)ca.w * 16 + j];
        uint4 v4 = xw4[(size_t)cb.x * 16 + j];
        uint4 v5 = xw4[(size_t)cb.y * 16 + j];
        uint4 v6 = xw4[(size_t)cb.z * 16 + j];
        uint4 v7 = xw4[(size_t)cb.w * 16 + j];
        const float w0 = rsqrtf((float)(g0 + 1));
        const float w1 = rsqrtf((float)(g1 + 1));
        const float w2 = rsqrtf((float)(g2 + 1));
        const float w3 = rsqrtf((float)(g3 + 1));
        const float w4 = rsqrtf((float)(g4 + 1));
        const float w5 = rsqrtf((float)(g5 + 1));
        const float w6 = rsqrtf((float)(g6 + 1));
        const float w7 = rsqrtf((float)(g7 + 1));
        ACC8(w0, v0) ACC8(w1, v1) ACC8(w2, v2) ACC8(w3, v3)
        ACC8(w4, v4) ACC8(w5, v5) ACC8(w6, v6) ACC8(w7, v7)
        p += 8;
    }
    if (p + 4 <= deg) {
        const int4 ca = *(const int4*)&slots[base + p];
        const int g0 = cnt[ca.x], g1 = cnt[ca.y], g2 = cnt[ca.z], g3 = cnt[ca.w];
        uint4 v0 = xw4[(size_t)ca.x * 16 + j];
        uint4 v1 = xw4[(size_t)ca.y * 16 + j];
        uint4 v2 = xw4[(size_t)ca.z * 16 + j];
        uint4 v3 = xw4[(size_t)ca.w * 16 + j];
        const float w0 = rsqrtf((float)(g0 + 1));
        const float w1 = rsqrtf((float)(g1 + 1));
        const float w2 = rsqrtf((float)(g2 + 1));
        const float w3 = rsqrtf((float)(g3 + 1));
        ACC8(w0, v0) ACC8(w1, v1) ACC8(w2, v2) ACC8(w3, v3)
        p += 4;
    }
    for (; p < deg; ++p) {
        const int s = slots[base + p];
        const float ww = rsqrtf((float)(cnt[s] + 1));
        uint4 vv = xw4[(size_t)s * 16 + j];
        ACC8(ww, vv)
    }
    uint4 vs = xw4[(size_t)node * 16 + j];
    float self[8] = { bflo(vs.x), bfhi(vs.x), bflo(vs.y), bfhi(vs.y),
                      bflo(vs.z), bfhi(vs.z), bflo(vs.w), bfhi(vs.w) };
    const float4 blo = ((const float4*)bias)[2 * j];
    const float4 bhi = ((const float4*)bias)[2 * j + 1];
    const float bb[8] = { blo.x, blo.y, blo.z, blo.w, bhi.x, bhi.y, bhi.z, bhi.w };
    const float dii = di * di;
    float o[8];
#pragma unroll
    for (int i = 0; i < 8; ++i) o[i] = di * acc[i] + dii * self[i] + bb[i];
    float* op = out + (size_t)node * 128 + j * 8;
    ((float4*)op)[0] = make_float4(o[0], o[1], o[2], o[3]);
    ((float4*)op)[1] = make_float4(o[4], o[5], o[6], o[7]);
    // relu'd bf16 copy for the next GEMM
    union { ushort us[8]; uint4 v; } pk;
#pragma unroll
    for (int i = 0; i < 8; ++i) pk.us[i] = f2bf(fmaxf(o[i], 0.f));
    ((uint4*)xwb)[(size_t)node * 16 + j] = pk.v;
}

// ---------------- aggregation layer 3 (Dout=64) + fused log_softmax --------------
__global__ __launch_bounds__(256) void agg3_lsm_kernel(
    const ushort* __restrict__ xw, const int* __restrict__ cnt,
    const int* __restrict__ slots, const float* __restrict__ bias,
    float* __restrict__ e3, float* __restrict__ logp, int n) {
    const int tid = threadIdx.x;
    const int node = blockIdx.x * 32 + (tid >> 3);
    const int j = tid & 7;
    if (node >= n) return;
    const uint4* xw4 = (const uint4*)xw;   // row pitch = 8 uint4
    const int degf = cnt[node];
    const int deg = (degf < SLOT_CAP) ? degf : SLOT_CAP;
    const float di = rsqrtf((float)(degf + 1));
    const int base = node << 6;
    float acc[8];
#pragma unroll
    for (int i = 0; i < 8; ++i) acc[i] = 0.f;

    int p = 0;
    while (p + 8 <= deg) {
        const int4 ca = *(const int4*)&slots[base + p];
        const int4 cb = *(const int4*)&slots[base + p + 4];
        const int g0 = cnt[ca.x], g1 = cnt[ca.y], g2 = cnt[ca.z], g3 = cnt[ca.w];
        const int g4 = cnt[cb.x], g5 = cnt[cb.y], g6 = cnt[cb.z], g7 = cnt[cb.w];
        uint4 v0 = xw4[(size_t)ca.x * 8 + j];
        uint4 v1 = xw4[(size_t)ca.y * 8 + j];
        uint4 v2 = xw4[(size_t)ca.z * 8 + j];
        uint4 v3 = xw4[(size_t)ca.w * 8 + j];
        uint4 v4 = xw4[(size_t)cb.x * 8 + j];
        uint4 v5 = xw4[(size_t)cb.y * 8 + j];
        uint4 v6 = xw4[(size_t)cb.z * 8 + j];
        uint4 v7 = xw4[(size_t)cb.w * 8 + j];
        const float w0 = rsqrtf((float)(g0 + 1));
        const float w1 = rsqrtf((float)(g1 + 1));
        const float w2 = rsqrtf((float)(g2 + 1));
        const float w3 = rsqrtf((float)(g3 + 1));
        const float w4 = rsqrtf((float)(g4 + 1));
        const float w5 = rsqrtf((float)(g5 + 1));
        const float w6 = rsqrtf((float)(g6 + 1));
        const float w7 = rsqrtf((float)(g7 + 1));
        ACC8(w0, v0) ACC8(w1, v1) ACC8(w2, v2) ACC8(w3, v3)
        ACC8(w4, v4) ACC8(w5, v5) ACC8(w6, v6) ACC8(w7, v7)
        p += 8;
    }
    if (p + 4 <= deg) {
        const int4 ca = *(const int4*)&slots[base + p];
        const int g0 = cnt[ca.x], g1 = cnt[ca.y], g2 = cnt[ca.z], g3 = cnt[ca.w];
        uint4 v0 = xw4[(size_t)ca.x * 8 + j];
        uint4 v1 = xw4[(size_t)ca.y * 8 + j];
        uint4 v2 = xw4[(size_t)ca.z * 8 + j];
        uint4 v3 = xw4[(size_t)ca.w * 8 + j];
        const float w0 = rsqrtf((float)(g0 + 1));
        const float w1 = rsqrtf((float)(g1 + 1));
        const float w2 = rsqrtf((float)(g2 + 1));
        const float w3 = rsqrtf((float)(g3 + 1));
        ACC8(w0, v0) ACC8(w1, v1) ACC8(w2, v2) ACC8(w3, v3)
        p += 4;
    }
    for (; p < deg; ++p) {
        const int s = slots[base + p];
        const float ww = rsqrtf((float)(cnt[s] + 1));
        uint4 vv = xw4[(size_t)s * 8 + j];
        ACC8(ww, vv)
    }
    uint4 vs = xw4[(size_t)node * 8 + j];
    float self[8] = { bflo(vs.x), bfhi(vs.x), bflo(vs.y), bfhi(vs.y),
                      bflo(vs.z), bfhi(vs.z), bflo(vs.w), bfhi(vs.w) };
    const float4 blo = ((const float4*)bias)[2 * j];
    const float4 bhi = ((const float4*)bias)[2 * j + 1];
    const float bb[8] = { blo.x, blo.y, blo.z, blo.w, bhi.x, bhi.y, bhi.z, bhi.w };
    const float dii = di * di;
    float o[8];
#pragma unroll
    for (int i = 0; i < 8; ++i) o[i] = di * acc[i] + dii * self[i] + bb[i];
    float* ep = e3 + (size_t)node * 64 + j * 8;
    ((float4*)ep)[0] = make_float4(o[0], o[1], o[2], o[3]);
    ((float4*)ep)[1] = make_float4(o[4], o[5], o[6], o[7]);
    // fused log_softmax over the 8-lane group
    float m = o[0];
#pragma unroll
    for (int i = 1; i < 8; ++i) m = fmaxf(m, o[i]);
#pragma unroll
    for (int off = 1; off < 8; off <<= 1) m = fmaxf(m, __shfl_xor(m, off, 64));
    float s = 0.f;
#pragma unroll
    for (int i = 0; i < 8; ++i) s += expf(o[i] - m);
#pragma unroll
    for (int off = 1; off < 8; off <<= 1) s += __shfl_xor(s, off, 64);
    const float ls = m + logf(s);
    float* lp = logp + (size_t)node * 64 + j * 8;
    ((float4*)lp)[0] = make_float4(o[0] - ls, o[1] - ls, o[2] - ls, o[3] - ls);
    ((float4*)lp)[1] = make_float4(o[4] - ls, o[5] - ls, o[6] - ls, o[7] - ls);
}

// ---------------- driver ----------------
extern "C" void kernel_launch(void* const* d_in, const int* in_sizes, int n_in,
                              void* d_out, int out_size, void* d_ws, size_t ws_size,
                              hipStream_t stream) {
    const float* x  = (const float*)d_in[0];
    const void*  ei = d_in[1];
    const float* W1 = (const float*)d_in[2];
    const float* b1 = (const float*)d_in[3];
    const float* W2 = (const float*)d_in[4];
    const float* b2 = (const float*)d_in[5];
    const float* W3 = (const float*)d_in[6];
    const float* b3 = (const float*)d_in[7];
    float* out = (float*)d_out;

    const int N = in_sizes[0] / 128;   // 50000
    const int E = in_sizes[1] / 2;     // 800000

    char* w = (char*)d_ws;
    size_t off = 0;
    auto alloc = [&](size_t bytes) -> void* {
        void* p = w + off;
        off = (off + bytes + 255) & ~(size_t)255;
        return p;
    };
    int*    cnt    = (int*)alloc((size_t)N * 4);
    int*    slots  = (int*)alloc((size_t)N * SLOT_CAP * 4);   // 12.8 MB
    ushort* xw     = (ushort*)alloc((size_t)N * 128 * 2);     // bf16 GEMM output
    ushort* xwb    = (ushort*)alloc((size_t)N * 128 * 2);     // bf16 relu'd agg output

    float* logp = out;
    float* e1 = out + (size_t)N * 64;
    float* e2 = e1 + (size_t)N * 128;
    float* e3 = e2 + (size_t)N * 128;

    const int nch = (E + FILL_CHUNK - 1) / FILL_CHUNK;   // edge chunks
    const int nfill = nch * 8;
    const int nper = (N + 7) / 8;                        // dst-partition width
    const int gblocks = (N + 127) / 128;

    hipMemsetAsync(cnt, 0, (size_t)N * 4, stream);
    // fused fill + gemm1
    k1_fill_gemm_kernel<<<nfill + gblocks, 256, 0, stream>>>(
        ei, E, nper, cnt, slots, x, W1, xw, N, nfill);
    // layer 1 aggregation
    agg12_kernel<<<(N + 15) / 16, 256, 0, stream>>>(xw, cnt, slots, b1, e1, xwb, N);
    // layer 2
    mfma_gemm_b_kernel<128><<<gblocks, 256, 0, stream>>>(xwb, W2, xw, N);
    agg12_kernel<<<(N + 15) / 16, 256, 0, stream>>>(xw, cnt, slots, b2, e2, xwb, N);
    // layer 3 (Dout=64) + log_softmax
    mfma_gemm_b_kernel<64><<<gblocks, 256, 0, stream>>>(xwb, W3, xw, N);
    agg3_lsm_kernel<<<(N + 31) / 32, 256, 0, stream>>>(xw, cnt, slots, b3, e3, logp, N);
}

// Round 8
// 273.875 us; speedup vs baseline: 1.0614x; 1.0614x over previous
//
#include <hip/hip_runtime.h>

// GCN_4492535792198: 3-layer GCN forward on MI355X (gfx950).
// N=50000, E=800000, D: 128->128->64. Outputs: logp[N,64], e1[N,128], e2[N,128], e3[N,64].
// R10: revert R9 fusion (gate hit: K1=75us, occupancy 23.7% from 34.8KB LDS on all
//   blocks + 3.2M bank conflicts in inline-W-transpose). Back to R7 structure
//   (prep + separate fill + LDS-staged GEMMs with prepacked Wt, measured 270.3us).
//   New: (a) slots as ushort (node ids < 65536) -> table 12.8->6.4MB: smaller scatter
//   footprint + halved slots traffic in all 3 agg passes; (b) nontemporal ei loads in
//   fill (streaming reads were evicting partially-dirty slot lines from L2 -> 44MB
//   WRITE for 3.2MB payload). 8 dispatches.

typedef __attribute__((ext_vector_type(8))) short short8;   // 8 x bf16 (4 VGPRs)
typedef __attribute__((ext_vector_type(4))) float f32x4;

#define SLOT_CAP 64
#define FILL_CHUNK 2048

__device__ __forceinline__ ushort f2bf(float f) {
    union { float f; unsigned u; } a; a.f = f;
    unsigned r = a.u + 0x7fffu + ((a.u >> 16) & 1u);   // RNE (finite data)
    return (ushort)(r >> 16);
}
__device__ __forceinline__ float bflo(unsigned u) { return __uint_as_float(u << 16); }
__device__ __forceinline__ float bfhi(unsigned u) { return __uint_as_float(u & 0xffff0000u); }

__device__ __forceinline__ int edge_at(const void* ei, int is64, long long i) {
    if (is64) return (int)((const long long*)ei)[i];
    return ((const int*)ei)[i];
}
// non-temporal variant: don't pollute L2 (protect slot-region residency)
__device__ __forceinline__ int edge_at_nt(const void* ei, int is64, long long i) {
    if (is64) return (int)__builtin_nontemporal_load(((const long long*)ei) + i);
    return __builtin_nontemporal_load(((const int*)ei) + i);
}

// ---------------- prep: zero cnt + weight transpose + detect dtype ----------------
// Wt[n][k] = bf16(W[k][n]). Grid = nzb + 161 blocks.
__global__ void prep_kernel(int* __restrict__ cnt, int n,
                            const float* __restrict__ W1, const float* __restrict__ W2,
                            const float* __restrict__ W3, ushort* __restrict__ Wt1,
                            ushort* __restrict__ Wt2, ushort* __restrict__ Wt3,
                            const void* ei, int* __restrict__ flag) {
    const int nzb = (n + 255) >> 8;
    const int b = blockIdx.x, tid = threadIdx.x;
    if (b < nzb) {
        int i = b * 256 + tid;
        if (i < n) cnt[i] = 0;
        return;
    }
    if (b == nzb + 160) {                 // dtype-detect block
        if (tid < 64) {
            long long v = ((const long long*)ei)[tid];
            int bad = (v < 0 || v >= (1LL << 32)) ? 1 : 0;
            unsigned long long m = __ballot(bad);
            if (tid == 0) *flag = (m == 0ULL) ? 1 : 0;   // 1 => int64
        }
        return;
    }
    int i = (b - nzb) * 256 + tid;
    if (i < 16384) {
        int nn = i >> 7, k = i & 127;
        Wt1[i] = f2bf(W1[k * 128 + nn]);
    } else if (i < 32768) {
        int j = i - 16384; int nn = j >> 7, k = j & 127;
        Wt2[j] = f2bf(W2[k * 128 + nn]);
    } else if (i < 40960) {
        int j = i - 32768; int nn = j >> 7, k = j & 127;
        Wt3[j] = f2bf(W3[k * 64 + nn]);
    }
}

// ---------------- XCD-partitioned slot fill (ushort slots, nt ei reads) ----------
// Block b: partition p = b&7 (dst range [p*nper, (p+1)*nper)), edge chunk c = b>>3.
__global__ void fillslots_kernel(const void* ei, const int* __restrict__ flag,
                                 int* __restrict__ cnt, ushort* __restrict__ slots,
                                 int E, int nper) {
    const int part = blockIdx.x & 7;
    const int lo = part * nper;
    const int hi = lo + nper;
    const int e0 = (blockIdx.x >> 3) * FILL_CHUNK;
    const int e1 = (e0 + FILL_CHUNK < E) ? e0 + FILL_CHUNK : E;
    const int is64 = flag[0];
    for (int e = e0 + threadIdx.x; e < e1; e += 256) {
        int d = edge_at_nt(ei, is64, (long long)E + e);
        if (d >= lo && d < hi) {
            int s = edge_at_nt(ei, is64, e);
            int p = atomicAdd(&cnt[d], 1);
            if (p < SLOT_CAP) slots[(d << 6) + p] = (ushort)s;
        }
    }
}

// ---------------- MFMA GEMM (fp32 input): xw[M,128](bf16) = A[M,128] @ W ----------
__global__ __launch_bounds__(256) void mfma_gemm_f32_kernel(
    const float* __restrict__ A, const ushort* __restrict__ Wt,
    ushort* __restrict__ xw, int M) {
    constexpr int NT = 8;
    __shared__ ushort As[128 * 136];
    __shared__ ushort Ws[128 * 136];
    const int tid = threadIdx.x;
    const int r0 = blockIdx.x * 128;
    const int wid = tid >> 6;
    const int lane = tid & 63;
    const int m = lane & 15, quad = lane >> 4;

#pragma unroll
    for (int i = 0; i < 16; ++i) {
        int li = tid + i * 256;             // 0..4095 float4 slots
        int row = li >> 5, c4 = li & 31;
        float4 v = make_float4(0.f, 0.f, 0.f, 0.f);
        int gr = r0 + row;
        if (gr < M) v = ((const float4*)(A + (size_t)gr * 128))[c4];
        ushort4 u;
        u.x = f2bf(v.x); u.y = f2bf(v.y); u.z = f2bf(v.z); u.w = f2bf(v.w);
        *(ushort4*)&As[row * 136 + c4 * 4] = u;
    }
#pragma unroll
    for (int i = 0; i < 8; ++i) {
        int li = tid + i * 256;             // uint4 slots over 128*16
        int n = li >> 4, c = li & 15;
        uint4 v = ((const uint4*)Wt)[li];
        *(uint4*)&Ws[n * 136 + c * 8] = v;
    }
    __syncthreads();

    f32x4 acc[2][NT];
#pragma unroll
    for (int rt = 0; rt < 2; ++rt)
#pragma unroll
        for (int nt = 0; nt < NT; ++nt) acc[rt][nt] = (f32x4){0.f, 0.f, 0.f, 0.f};

#pragma unroll
    for (int kt = 0; kt < 4; ++kt) {
        const int ko = kt * 32 + quad * 8;
        short8 af0 = *(const short8*)&As[(wid * 32 + m) * 136 + ko];
        short8 af1 = *(const short8*)&As[(wid * 32 + 16 + m) * 136 + ko];
        short8 bfr[NT];
#pragma unroll
        for (int nt = 0; nt < NT; ++nt)
            bfr[nt] = *(const short8*)&Ws[(nt * 16 + m) * 136 + ko];
#pragma unroll
        for (int nt = 0; nt < NT; ++nt) {
            acc[0][nt] = __builtin_amdgcn_mfma_f32_16x16x32_bf16(af0, bfr[nt], acc[0][nt], 0, 0, 0);
            acc[1][nt] = __builtin_amdgcn_mfma_f32_16x16x32_bf16(af1, bfr[nt], acc[1][nt], 0, 0, 0);
        }
    }
#pragma unroll
    for (int rt = 0; rt < 2; ++rt)
#pragma unroll
        for (int nt = 0; nt < NT; ++nt)
#pragma unroll
            for (int i = 0; i < 4; ++i) {
                int row = r0 + wid * 32 + rt * 16 + quad * 4 + i;
                if (row < M) xw[(size_t)row * 128 + nt * 16 + m] = f2bf(acc[rt][nt][i]);
            }
}

// ---------------- MFMA GEMM (bf16 input, pre-relu'd): xw = A @ W ----------------
template <int DOUT>
__global__ __launch_bounds__(256) void mfma_gemm_b_kernel(
    const ushort* __restrict__ A, const ushort* __restrict__ Wt,
    ushort* __restrict__ xw, int M) {
    constexpr int NT = DOUT / 16;
    __shared__ ushort As[128 * 136];
    __shared__ ushort Ws[DOUT * 136];
    const int tid = threadIdx.x;
    const int r0 = blockIdx.x * 128;
    const int wid = tid >> 6;
    const int lane = tid & 63;
    const int m = lane & 15, quad = lane >> 4;

#pragma unroll
    for (int i = 0; i < 8; ++i) {
        int li = tid + i * 256;             // 2048 uint4 slots (128 rows x 16)
        int row = li >> 4, c = li & 15;
        uint4 v = make_uint4(0u, 0u, 0u, 0u);
        int gr = r0 + row;
        if (gr < M) v = ((const uint4*)A)[(size_t)gr * 16 + c];
        *(uint4*)&As[row * 136 + c * 8] = v;
    }
#pragma unroll
    for (int i = 0; i < DOUT / 16; ++i) {
        int li = tid + i * 256;             // uint4 slots over DOUT*16
        int n = li >> 4, c = li & 15;
        uint4 v = ((const uint4*)Wt)[li];
        *(uint4*)&Ws[n * 136 + c * 8] = v;
    }
    __syncthreads();

    f32x4 acc[2][NT];
#pragma unroll
    for (int rt = 0; rt < 2; ++rt)
#pragma unroll
        for (int nt = 0; nt < NT; ++nt) acc[rt][nt] = (f32x4){0.f, 0.f, 0.f, 0.f};

#pragma unroll
    for (int kt = 0; kt < 4; ++kt) {
        const int ko = kt * 32 + quad * 8;
        short8 af0 = *(const short8*)&As[(wid * 32 + m) * 136 + ko];
        short8 af1 = *(const short8*)&As[(wid * 32 + 16 + m) * 136 + ko];
        short8 bfr[NT];
#pragma unroll
        for (int nt = 0; nt < NT; ++nt)
            bfr[nt] = *(const short8*)&Ws[(nt * 16 + m) * 136 + ko];
#pragma unroll
        for (int nt = 0; nt < NT; ++nt) {
            acc[0][nt] = __builtin_amdgcn_mfma_f32_16x16x32_bf16(af0, bfr[nt], acc[0][nt], 0, 0, 0);
            acc[1][nt] = __builtin_amdgcn_mfma_f32_16x16x32_bf16(af1, bfr[nt], acc[1][nt], 0, 0, 0);
        }
    }
#pragma unroll
    for (int rt = 0; rt < 2; ++rt)
#pragma unroll
        for (int nt = 0; nt < NT; ++nt)
#pragma unroll
            for (int i = 0; i < 4; ++i) {
                int row = r0 + wid * 32 + rt * 16 + quad * 4 + i;
                if (row < M) xw[(size_t)row * DOUT + nt * 16 + m] = f2bf(acc[rt][nt][i]);
            }
}

// NOTE: parameter names must not collide with vector member names (.x/.y/.z/.w).
#define ACC8(W_, V_)                                               \
    acc[0] += W_ * bflo(V_.x); acc[1] += W_ * bfhi(V_.x);          \
    acc[2] += W_ * bflo(V_.y); acc[3] += W_ * bfhi(V_.y);          \
    acc[4] += W_ * bflo(V_.z); acc[5] += W_ * bfhi(V_.z);          \
    acc[6] += W_ * bflo(V_.w); acc[7] += W_ * bfhi(V_.w);

// ---------------- aggregation layers 1/2 (bf16 gather, ushort slots, 8-deep) -----
__global__ __launch_bounds__(256) void agg12_kernel(
    const ushort* __restrict__ xw, const int* __restrict__ cnt,
    const ushort* __restrict__ slots, const float* __restrict__ bias,
    float* __restrict__ out, ushort* __restrict__ xwb, int n) {
    const int tid = threadIdx.x;
    const int node = blockIdx.x * 16 + (tid >> 4);
    const int j = tid & 15;
    if (node >= n) return;
    const uint4* xw4 = (const uint4*)xw;   // row pitch = 16 uint4
    const int degf = cnt[node];
    const int deg = (degf < SLOT_CAP) ? degf : SLOT_CAP;
    const float di = rsqrtf((float)(degf + 1));
    const int base = node << 6;
    float acc[8];
#pragma unroll
    for (int i = 0; i < 8; ++i) acc[i] = 0.f;

    int p = 0;
    while (p + 8 <= deg) {
        const uint4 cw = *(const uint4*)&slots[base + p];   // 8 ushort sources
        const int s0 = cw.x & 0xffff, s1 = cw.x >> 16;
        const int s2 = cw.y & 0xffff, s3 = cw.y >> 16;
        const int s4 = cw.z & 0xffff, s5 = cw.z >> 16;
        const int s6 = cw.w & 0xffff, s7 = cw.w >> 16;
        const int g0 = cnt[s0], g1 = cnt[s1], g2 = cnt[s2], g3 = cnt[s3];
        const int g4 = cnt[s4], g5 = cnt[s5], g6 = cnt[s6], g7 = cnt[s7];
        uint4 v0 = xw4[(size_t)s0 * 16 + j];
        uint4 v1 = xw4[(size_t)s1 * 16 + j];
        uint4 v2 = xw4[(size_t)s2 * 16 + j];
        uint4 v3 = xw4[(size_t)s3 * 16 + j];
        uint4 v4 = xw4[(size_t)s4 * 16 + j];
        uint4 v5 = xw4[(size_t)s5 * 16 + j];
        uint4 v6 = xw4[(size_t)s6 * 16 + j];
        uint4 v7 = xw4[(size_t)s7 * 16 + j];
        const float w0 = rsqrtf((float)(g0 + 1));
        const float w1 = rsqrtf((float)(g1 + 1));
        const float w2 = rsqrtf((float)(g2 + 1));
        const float w3 = rsqrtf((float)(g3 + 1));
        const float w4 = rsqrtf((float)(g4 + 1));
        const float w5 = rsqrtf((float)(g5 + 1));
        const float w6 = rsqrtf((float)(g6 + 1));
        const float w7 = rsqrtf((float)(g7 + 1));
        ACC8(w0, v0) ACC8(w1, v1) ACC8(w2, v2) ACC8(w3, v3)
        ACC8(w4, v4) ACC8(w5, v5) ACC8(w6, v6) ACC8(w7, v7)
        p += 8;
    }
    if (p + 4 <= deg) {
        const uint2 cw = *(const uint2*)&slots[base + p];
        const int s0 = cw.x & 0xffff, s1 = cw.x >> 16;
        const int s2 = cw.y & 0xffff, s3 = cw.y >> 16;
        const int g0 = cnt[s0], g1 = cnt[s1], g2 = cnt[s2], g3 = cnt[s3];
        uint4 v0 = xw4[(size_t)s0 * 16 + j];
        uint4 v1 = xw4[(size_t)s1 * 16 + j];
        uint4 v2 = xw4[(size_t)s2 * 16 + j];
        uint4 v3 = xw4[(size_t)s3 * 16 + j];
        const float w0 = rsqrtf((float)(g0 + 1));
        const float w1 = rsqrtf((float)(g1 + 1));
        const float w2 = rsqrtf((float)(g2 + 1));
        const float w3 = rsqrtf((float)(g3 + 1));
        ACC8(w0, v0) ACC8(w1, v1) ACC8(w2, v2) ACC8(w3, v3)
        p += 4;
    }
    for (; p < deg; ++p) {
        const int s = slots[base + p];
        const float ww = rsqrtf((float)(cnt[s] + 1));
        uint4 vv = xw4[(size_t)s * 16 + j];
        ACC8(ww, vv)
    }
    uint4 vs = xw4[(size_t)node * 16 + j];
    float self[8] = { bflo(vs.x), bfhi(vs.x), bflo(vs.y), bfhi(vs.y),
                      bflo(vs.z), bfhi(vs.z), bflo(vs.w), bfhi(vs.w) };
    const float4 blo = ((const float4*)bias)[2 * j];
    const float4 bhi = ((const float4*)bias)[2 * j + 1];
    const float bb[8] = { blo.x, blo.y, blo.z, blo.w, bhi.x, bhi.y, bhi.z, bhi.w };
    const float dii = di * di;
    float o[8];
#pragma unroll
    for (int i = 0; i < 8; ++i) o[i] = di * acc[i] + dii * self[i] + bb[i];
    float* op = out + (size_t)node * 128 + j * 8;
    ((float4*)op)[0] = make_float4(o[0], o[1], o[2], o[3]);
    ((float4*)op)[1] = make_float4(o[4], o[5], o[6], o[7]);
    // relu'd bf16 copy for the next GEMM
    union { ushort us[8]; uint4 v; } pk;
#pragma unroll
    for (int i = 0; i < 8; ++i) pk.us[i] = f2bf(fmaxf(o[i], 0.f));
    ((uint4*)xwb)[(size_t)node * 16 + j] = pk.v;
}

// ---------------- aggregation layer 3 (Dout=64) + fused log_softmax --------------
__global__ __launch_bounds__(256) void agg3_lsm_kernel(
    const ushort* __restrict__ xw, const int* __restrict__ cnt,
    const ushort* __restrict__ slots, const float* __restrict__ bias,
    float* __restrict__ e3, float* __restrict__ logp, int n) {
    const int tid = threadIdx.x;
    const int node = blockIdx.x * 32 + (tid >> 3);
    const int j = tid & 7;
    if (node >= n) return;
    const uint4* xw4 = (const uint4*)xw;   // row pitch = 8 uint4
    const int degf = cnt[node];
    const int deg = (degf < SLOT_CAP) ? degf : SLOT_CAP;
    const float di = rsqrtf((float)(degf + 1));
    const int base = node << 6;
    float acc[8];
#pragma unroll
    for (int i = 0; i < 8; ++i) acc[i] = 0.f;

    int p = 0;
    while (p + 8 <= deg) {
        const uint4 cw = *(const uint4*)&slots[base + p];
        const int s0 = cw.x & 0xffff, s1 = cw.x >> 16;
        const int s2 = cw.y & 0xffff, s3 = cw.y >> 16;
        const int s4 = cw.z & 0xffff, s5 = cw.z >> 16;
        const int s6 = cw.w & 0xffff, s7 = cw.w >> 16;
        const int g0 = cnt[s0], g1 = cnt[s1], g2 = cnt[s2], g3 = cnt[s3];
        const int g4 = cnt[s4], g5 = cnt[s5], g6 = cnt[s6], g7 = cnt[s7];
        uint4 v0 = xw4[(size_t)s0 * 8 + j];
        uint4 v1 = xw4[(size_t)s1 * 8 + j];
        uint4 v2 = xw4[(size_t)s2 * 8 + j];
        uint4 v3 = xw4[(size_t)s3 * 8 + j];
        uint4 v4 = xw4[(size_t)s4 * 8 + j];
        uint4 v5 = xw4[(size_t)s5 * 8 + j];
        uint4 v6 = xw4[(size_t)s6 * 8 + j];
        uint4 v7 = xw4[(size_t)s7 * 8 + j];
        const float w0 = rsqrtf((float)(g0 + 1));
        const float w1 = rsqrtf((float)(g1 + 1));
        const float w2 = rsqrtf((float)(g2 + 1));
        const float w3 = rsqrtf((float)(g3 + 1));
        const float w4 = rsqrtf((float)(g4 + 1));
        const float w5 = rsqrtf((float)(g5 + 1));
        const float w6 = rsqrtf((float)(g6 + 1));
        const float w7 = rsqrtf((float)(g7 + 1));
        ACC8(w0, v0) ACC8(w1, v1) ACC8(w2, v2) ACC8(w3, v3)
        ACC8(w4, v4) ACC8(w5, v5) ACC8(w6, v6) ACC8(w7, v7)
        p += 8;
    }
    if (p + 4 <= deg) {
        const uint2 cw = *(const uint2*)&slots[base + p];
        const int s0 = cw.x & 0xffff, s1 = cw.x >> 16;
        const int s2 = cw.y & 0xffff, s3 = cw.y >> 16;
        const int g0 = cnt[s0], g1 = cnt[s1], g2 = cnt[s2], g3 = cnt[s3];
        uint4 v0 = xw4[(size_t)s0 * 8 + j];
        uint4 v1 = xw4[(size_t)s1 * 8 + j];
        uint4 v2 = xw4[(size_t)s2 * 8 + j];
        uint4 v3 = xw4[(size_t)s3 * 8 + j];
        const float w0 = rsqrtf((float)(g0 + 1));
        const float w1 = rsqrtf((float)(g1 + 1));
        const float w2 = rsqrtf((float)(g2 + 1));
        const float w3 = rsqrtf((float)(g3 + 1));
        ACC8(w0, v0) ACC8(w1, v1) ACC8(w2, v2) ACC8(w3, v3)
        p += 4;
    }
    for (; p < deg; ++p) {
        const int s = slots[base + p];
        const float ww = rsqrtf((float)(cnt[s] + 1));
        uint4 vv = xw4[(size_t)s * 8 + j];
        ACC8(ww, vv)
    }
    uint4 vs = xw4[(size_t)node * 8 + j];
    float self[8] = { bflo(vs.x), bfhi(vs.x), bflo(vs.y), bfhi(vs.y),
                      bflo(vs.z), bfhi(vs.z), bflo(vs.w), bfhi(vs.w) };
    const float4 blo = ((const float4*)bias)[2 * j];
    const float4 bhi = ((const float4*)bias)[2 * j + 1];
    const float bb[8] = { blo.x, blo.y, blo.z, blo.w, bhi.x, bhi.y, bhi.z, bhi.w };
    const float dii = di * di;
    float o[8];
#pragma unroll
    for (int i = 0; i < 8; ++i) o[i] = di * acc[i] + dii * self[i] + bb[i];
    float* ep = e3 + (size_t)node * 64 + j * 8;
    ((float4*)ep)[0] = make_float4(o[0], o[1], o[2], o[3]);
    ((float4*)ep)[1] = make_float4(o[4], o[5], o[6], o[7]);
    // fused log_softmax over the 8-lane group
    float m = o[0];
#pragma unroll
    for (int i = 1; i < 8; ++i) m = fmaxf(m, o[i]);
#pragma unroll
    for (int off = 1; off < 8; off <<= 1) m = fmaxf(m, __shfl_xor(m, off, 64));
    float s = 0.f;
#pragma unroll
    for (int i = 0; i < 8; ++i) s += expf(o[i] - m);
#pragma unroll
    for (int off = 1; off < 8; off <<= 1) s += __shfl_xor(s, off, 64);
    const float ls = m + logf(s);
    float* lp = logp + (size_t)node * 64 + j * 8;
    ((float4*)lp)[0] = make_float4(o[0] - ls, o[1] - ls, o[2] - ls, o[3] - ls);
    ((float4*)lp)[1] = make_float4(o[4] - ls, o[5] - ls, o[6] - ls, o[7] - ls);
}

// ---------------- driver ----------------
extern "C" void kernel_launch(void* const* d_in, const int* in_sizes, int n_in,
                              void* d_out, int out_size, void* d_ws, size_t ws_size,
                              hipStream_t stream) {
    const float* x  = (const float*)d_in[0];
    const void*  ei = d_in[1];
    const float* W1 = (const float*)d_in[2];
    const float* b1 = (const float*)d_in[3];
    const float* W2 = (const float*)d_in[4];
    const float* b2 = (const float*)d_in[5];
    const float* W3 = (const float*)d_in[6];
    const float* b3 = (const float*)d_in[7];
    float* out = (float*)d_out;

    const int N = in_sizes[0] / 128;   // 50000
    const int E = in_sizes[1] / 2;     // 800000

    char* w = (char*)d_ws;
    size_t off = 0;
    auto alloc = [&](size_t bytes) -> void* {
        void* p = w + off;
        off = (off + bytes + 255) & ~(size_t)255;
        return p;
    };
    int*    flag   = (int*)alloc(4);
    int*    cnt    = (int*)alloc((size_t)N * 4);
    ushort* slots  = (ushort*)alloc((size_t)N * SLOT_CAP * 2);  // 6.4 MB
    ushort* xw     = (ushort*)alloc((size_t)N * 128 * 2);       // bf16 GEMM output
    ushort* xwb    = (ushort*)alloc((size_t)N * 128 * 2);       // bf16 relu'd agg output
    ushort* Wt1    = (ushort*)alloc(16384 * 2);
    ushort* Wt2    = (ushort*)alloc(16384 * 2);
    ushort* Wt3    = (ushort*)alloc(8192 * 2);

    float* logp = out;
    float* e1 = out + (size_t)N * 64;
    float* e2 = e1 + (size_t)N * 128;
    float* e3 = e2 + (size_t)N * 128;

    const int nzb = (N + 255) / 256;
    const int nper = (N + 7) / 8;                      // dst-partition width
    const int nch = (E + FILL_CHUNK - 1) / FILL_CHUNK; // edge chunks

    prep_kernel<<<nzb + 161, 256, 0, stream>>>(cnt, N, W1, W2, W3, Wt1, Wt2, Wt3,
                                               ei, flag);
    fillslots_kernel<<<nch * 8, 256, 0, stream>>>(ei, flag, cnt, slots, E, nper);

    const int gblocks = (N + 127) / 128;
    // layer 1
    mfma_gemm_f32_kernel<<<gblocks, 256, 0, stream>>>(x, Wt1, xw, N);
    agg12_kernel<<<(N + 15) / 16, 256, 0, stream>>>(xw, cnt, slots, b1, e1, xwb, N);
    // layer 2
    mfma_gemm_b_kernel<128><<<gblocks, 256, 0, stream>>>(xwb, Wt2, xw, N);
    agg12_kernel<<<(N + 15) / 16, 256, 0, stream>>>(xw, cnt, slots, b2, e2, xwb, N);
    // layer 3 (Dout=64) + log_softmax
    mfma_gemm_b_kernel<64><<<gblocks, 256, 0, stream>>>(xwb, Wt3, xw, N);
    agg3_lsm_kernel<<<(N + 31) / 32, 256, 0, stream>>>(xw, cnt, slots, b3, e3, logp, N);
}

// Round 9
// 271.398 us; speedup vs baseline: 1.0711x; 1.0091x over previous
//
#include <hip/hip_runtime.h>

// GCN_4492535792198: 3-layer GCN forward on MI355X (gfx950).
// N=50000, E=800000, D: 128->128->64. Outputs: logp[N,64], e1[N,128], e2[N,128], e3[N,64].
// R11: (a) dinv-prescaled GEMM epilogue — xw rows are scaled by dinv[row] at the
//   GEMM, so aggregation is a pure gather-sum: out = di*(sum_s xw[s] + xw[node]) + b
//   (self term: di*(di*xw) = di^2*xw, exact). Removes per-edge cnt gather + rsqrt +
//   weight multiply from all 3 agg kernels. (b) prep folded into fill launch as
//   heterogeneous blocks (both LDS-free; fill does per-wave dtype detect, no flag).
//   7 dispatches. Slots stay ushort; nt ei loads kept (neutral, smaller footprint).

typedef __attribute__((ext_vector_type(8))) short short8;   // 8 x bf16 (4 VGPRs)
typedef __attribute__((ext_vector_type(4))) float f32x4;

#define SLOT_CAP 64
#define FILL_CHUNK 2048

__device__ __forceinline__ ushort f2bf(float f) {
    union { float f; unsigned u; } a; a.f = f;
    unsigned r = a.u + 0x7fffu + ((a.u >> 16) & 1u);   // RNE (finite data)
    return (ushort)(r >> 16);
}
__device__ __forceinline__ float bflo(unsigned u) { return __uint_as_float(u << 16); }
__device__ __forceinline__ float bfhi(unsigned u) { return __uint_as_float(u & 0xffff0000u); }

__device__ __forceinline__ int edge_at_nt(const void* ei, int is64, long long i) {
    if (is64) return (int)__builtin_nontemporal_load(((const long long*)ei) + i);
    return __builtin_nontemporal_load(((const int*)ei) + i);
}

// ---------------- fused: XCD-partitioned slot fill + weight-transpose prep --------
// blocks [0, nfill): fill role — partition b&7, edge chunk b>>3, per-wave dtype
// detect (no flag dependency). blocks [nfill, nfill+160): Wt[n][k] = bf16(W[k][n]).
__global__ void fill_prep_kernel(const void* ei, int E, int nper,
                                 int* __restrict__ cnt, ushort* __restrict__ slots,
                                 const float* __restrict__ W1,
                                 const float* __restrict__ W2,
                                 const float* __restrict__ W3,
                                 ushort* __restrict__ Wt1, ushort* __restrict__ Wt2,
                                 ushort* __restrict__ Wt3, int nfill) {
    const int b = blockIdx.x;
    const int tid = threadIdx.x;
    if (b < nfill) {
        const int lane = tid & 63;
        long long v64 = ((const long long*)ei)[lane];
        int bad = (v64 < 0 || v64 >= (1LL << 32)) ? 1 : 0;
        unsigned long long mm = __ballot(bad);
        const int is64 = (mm == 0ULL) ? 1 : 0;
        const int part = b & 7;
        const int lo = part * nper;
        const int hi = lo + nper;
        const int e0 = (b >> 3) * FILL_CHUNK;
        const int e1 = (e0 + FILL_CHUNK < E) ? e0 + FILL_CHUNK : E;
        for (int e = e0 + tid; e < e1; e += 256) {
            int d = edge_at_nt(ei, is64, (long long)E + e);
            if (d >= lo && d < hi) {
                int s = edge_at_nt(ei, is64, e);
                int p = atomicAdd(&cnt[d], 1);
                if (p < SLOT_CAP) slots[(d << 6) + p] = (ushort)s;
            }
        }
        return;
    }
    int i = (b - nfill) * 256 + tid;
    if (i < 16384) {
        int nn = i >> 7, k = i & 127;
        Wt1[i] = f2bf(W1[k * 128 + nn]);
    } else if (i < 32768) {
        int j = i - 16384; int nn = j >> 7, k = j & 127;
        Wt2[j] = f2bf(W2[k * 128 + nn]);
    } else if (i < 40960) {
        int j = i - 32768; int nn = j >> 7, k = j & 127;
        Wt3[j] = f2bf(W3[k * 64 + nn]);
    }
}

// ---------------- MFMA GEMM (fp32 input): xw[M,128](bf16) = dinv ⊙ (A @ W) --------
// Epilogue scales each output row by dinv[row] = rsqrt(cnt[row]+1).
__global__ __launch_bounds__(256) void mfma_gemm_f32_kernel(
    const float* __restrict__ A, const ushort* __restrict__ Wt,
    const int* __restrict__ cnt, ushort* __restrict__ xw, int M) {
    constexpr int NT = 8;
    __shared__ ushort As[128 * 136];
    __shared__ ushort Ws[128 * 136];
    const int tid = threadIdx.x;
    const int r0 = blockIdx.x * 128;
    const int wid = tid >> 6;
    const int lane = tid & 63;
    const int m = lane & 15, quad = lane >> 4;

#pragma unroll
    for (int i = 0; i < 16; ++i) {
        int li = tid + i * 256;             // 0..4095 float4 slots
        int row = li >> 5, c4 = li & 31;
        float4 v = make_float4(0.f, 0.f, 0.f, 0.f);
        int gr = r0 + row;
        if (gr < M) v = ((const float4*)(A + (size_t)gr * 128))[c4];
        ushort4 u;
        u.x = f2bf(v.x); u.y = f2bf(v.y); u.z = f2bf(v.z); u.w = f2bf(v.w);
        *(ushort4*)&As[row * 136 + c4 * 4] = u;
    }
#pragma unroll
    for (int i = 0; i < 8; ++i) {
        int li = tid + i * 256;             // uint4 slots over 128*16
        int n = li >> 4, c = li & 15;
        uint4 v = ((const uint4*)Wt)[li];
        *(uint4*)&Ws[n * 136 + c * 8] = v;
    }
    __syncthreads();

    f32x4 acc[2][NT];
#pragma unroll
    for (int rt = 0; rt < 2; ++rt)
#pragma unroll
        for (int nt = 0; nt < NT; ++nt) acc[rt][nt] = (f32x4){0.f, 0.f, 0.f, 0.f};

#pragma unroll
    for (int kt = 0; kt < 4; ++kt) {
        const int ko = kt * 32 + quad * 8;
        short8 af0 = *(const short8*)&As[(wid * 32 + m) * 136 + ko];
        short8 af1 = *(const short8*)&As[(wid * 32 + 16 + m) * 136 + ko];
        short8 bfr[NT];
#pragma unroll
        for (int nt = 0; nt < NT; ++nt)
            bfr[nt] = *(const short8*)&Ws[(nt * 16 + m) * 136 + ko];
#pragma unroll
        for (int nt = 0; nt < NT; ++nt) {
            acc[0][nt] = __builtin_amdgcn_mfma_f32_16x16x32_bf16(af0, bfr[nt], acc[0][nt], 0, 0, 0);
            acc[1][nt] = __builtin_amdgcn_mfma_f32_16x16x32_bf16(af1, bfr[nt], acc[1][nt], 0, 0, 0);
        }
    }
#pragma unroll
    for (int rt = 0; rt < 2; ++rt)
#pragma unroll
        for (int i = 0; i < 4; ++i) {
            int row = r0 + wid * 32 + rt * 16 + quad * 4 + i;
            if (row < M) {
                const float di = rsqrtf((float)(cnt[row] + 1));
#pragma unroll
                for (int nt = 0; nt < NT; ++nt)
                    xw[(size_t)row * 128 + nt * 16 + m] = f2bf(acc[rt][nt][i] * di);
            }
        }
}

// ---------------- MFMA GEMM (bf16 input, pre-relu'd): xw = dinv ⊙ (A @ W) --------
template <int DOUT>
__global__ __launch_bounds__(256) void mfma_gemm_b_kernel(
    const ushort* __restrict__ A, const ushort* __restrict__ Wt,
    const int* __restrict__ cnt, ushort* __restrict__ xw, int M) {
    constexpr int NT = DOUT / 16;
    __shared__ ushort As[128 * 136];
    __shared__ ushort Ws[DOUT * 136];
    const int tid = threadIdx.x;
    const int r0 = blockIdx.x * 128;
    const int wid = tid >> 6;
    const int lane = tid & 63;
    const int m = lane & 15, quad = lane >> 4;

#pragma unroll
    for (int i = 0; i < 8; ++i) {
        int li = tid + i * 256;             // 2048 uint4 slots (128 rows x 16)
        int row = li >> 4, c = li & 15;
        uint4 v = make_uint4(0u, 0u, 0u, 0u);
        int gr = r0 + row;
        if (gr < M) v = ((const uint4*)A)[(size_t)gr * 16 + c];
        *(uint4*)&As[row * 136 + c * 8] = v;
    }
#pragma unroll
    for (int i = 0; i < DOUT / 16; ++i) {
        int li = tid + i * 256;             // uint4 slots over DOUT*16
        int n = li >> 4, c = li & 15;
        uint4 v = ((const uint4*)Wt)[li];
        *(uint4*)&Ws[n * 136 + c * 8] = v;
    }
    __syncthreads();

    f32x4 acc[2][NT];
#pragma unroll
    for (int rt = 0; rt < 2; ++rt)
#pragma unroll
        for (int nt = 0; nt < NT; ++nt) acc[rt][nt] = (f32x4){0.f, 0.f, 0.f, 0.f};

#pragma unroll
    for (int kt = 0; kt < 4; ++kt) {
        const int ko = kt * 32 + quad * 8;
        short8 af0 = *(const short8*)&As[(wid * 32 + m) * 136 + ko];
        short8 af1 = *(const short8*)&As[(wid * 32 + 16 + m) * 136 + ko];
        short8 bfr[NT];
#pragma unroll
        for (int nt = 0; nt < NT; ++nt)
            bfr[nt] = *(const short8*)&Ws[(nt * 16 + m) * 136 + ko];
#pragma unroll
        for (int nt = 0; nt < NT; ++nt) {
            acc[0][nt] = __builtin_amdgcn_mfma_f32_16x16x32_bf16(af0, bfr[nt], acc[0][nt], 0, 0, 0);
            acc[1][nt] = __builtin_amdgcn_mfma_f32_16x16x32_bf16(af1, bfr[nt], acc[1][nt], 0, 0, 0);
        }
    }
#pragma unroll
    for (int rt = 0; rt < 2; ++rt)
#pragma unroll
        for (int i = 0; i < 4; ++i) {
            int row = r0 + wid * 32 + rt * 16 + quad * 4 + i;
            if (row < M) {
                const float di = rsqrtf((float)(cnt[row] + 1));
#pragma unroll
                for (int nt = 0; nt < NT; ++nt)
                    xw[(size_t)row * DOUT + nt * 16 + m] = f2bf(acc[rt][nt][i] * di);
            }
        }
}

// NOTE: parameter names must not collide with vector member names (.x/.y/.z/.w).
#define ADD8(V_)                                       \
    acc[0] += bflo(V_.x); acc[1] += bfhi(V_.x);        \
    acc[2] += bflo(V_.y); acc[3] += bfhi(V_.y);        \
    acc[4] += bflo(V_.z); acc[5] += bfhi(V_.z);        \
    acc[6] += bflo(V_.w); acc[7] += bfhi(V_.w);

// ---------------- aggregation layers 1/2 (pure gather-sum, 8-deep) ---------------
// out = di*(sum_s xw[s] + xw[node]) + b  (xw rows pre-scaled by dinv at the GEMM).
__global__ __launch_bounds__(256) void agg12_kernel(
    const ushort* __restrict__ xw, const int* __restrict__ cnt,
    const ushort* __restrict__ slots, const float* __restrict__ bias,
    float* __restrict__ out, ushort* __restrict__ xwb, int n) {
    const int tid = threadIdx.x;
    const int node = blockIdx.x * 16 + (tid >> 4);
    const int j = tid & 15;
    if (node >= n) return;
    const uint4* xw4 = (const uint4*)xw;   // row pitch = 16 uint4
    const int degf = cnt[node];
    const int deg = (degf < SLOT_CAP) ? degf : SLOT_CAP;
    const float di = rsqrtf((float)(degf + 1));
    const int base = node << 6;
    float acc[8];
#pragma unroll
    for (int i = 0; i < 8; ++i) acc[i] = 0.f;

    int p = 0;
    while (p + 8 <= deg) {
        const uint4 cw = *(const uint4*)&slots[base + p];   // 8 ushort sources
        const int s0 = cw.x & 0xffff, s1 = cw.x >> 16;
        const int s2 = cw.y & 0xffff, s3 = cw.y >> 16;
        const int s4 = cw.z & 0xffff, s5 = cw.z >> 16;
        const int s6 = cw.w & 0xffff, s7 = cw.w >> 16;
        uint4 v0 = xw4[(size_t)s0 * 16 + j];
        uint4 v1 = xw4[(size_t)s1 * 16 + j];
        uint4 v2 = xw4[(size_t)s2 * 16 + j];
        uint4 v3 = xw4[(size_t)s3 * 16 + j];
        uint4 v4 = xw4[(size_t)s4 * 16 + j];
        uint4 v5 = xw4[(size_t)s5 * 16 + j];
        uint4 v6 = xw4[(size_t)s6 * 16 + j];
        uint4 v7 = xw4[(size_t)s7 * 16 + j];
        ADD8(v0) ADD8(v1) ADD8(v2) ADD8(v3)
        ADD8(v4) ADD8(v5) ADD8(v6) ADD8(v7)
        p += 8;
    }
    if (p + 4 <= deg) {
        const uint2 cw = *(const uint2*)&slots[base + p];
        const int s0 = cw.x & 0xffff, s1 = cw.x >> 16;
        const int s2 = cw.y & 0xffff, s3 = cw.y >> 16;
        uint4 v0 = xw4[(size_t)s0 * 16 + j];
        uint4 v1 = xw4[(size_t)s1 * 16 + j];
        uint4 v2 = xw4[(size_t)s2 * 16 + j];
        uint4 v3 = xw4[(size_t)s3 * 16 + j];
        ADD8(v0) ADD8(v1) ADD8(v2) ADD8(v3)
        p += 4;
    }
    for (; p < deg; ++p) {
        const int s = slots[base + p];
        uint4 vv = xw4[(size_t)s * 16 + j];
        ADD8(vv)
    }
    uint4 vs = xw4[(size_t)node * 16 + j];
    acc[0] += bflo(vs.x); acc[1] += bfhi(vs.x);
    acc[2] += bflo(vs.y); acc[3] += bfhi(vs.y);
    acc[4] += bflo(vs.z); acc[5] += bfhi(vs.z);
    acc[6] += bflo(vs.w); acc[7] += bfhi(vs.w);
    const float4 blo = ((const float4*)bias)[2 * j];
    const float4 bhi = ((const float4*)bias)[2 * j + 1];
    const float bb[8] = { blo.x, blo.y, blo.z, blo.w, bhi.x, bhi.y, bhi.z, bhi.w };
    float o[8];
#pragma unroll
    for (int i = 0; i < 8; ++i) o[i] = di * acc[i] + bb[i];
    float* op = out + (size_t)node * 128 + j * 8;
    ((float4*)op)[0] = make_float4(o[0], o[1], o[2], o[3]);
    ((float4*)op)[1] = make_float4(o[4], o[5], o[6], o[7]);
    // relu'd bf16 copy for the next GEMM
    union { ushort us[8]; uint4 v; } pk;
#pragma unroll
    for (int i = 0; i < 8; ++i) pk.us[i] = f2bf(fmaxf(o[i], 0.f));
    ((uint4*)xwb)[(size_t)node * 16 + j] = pk.v;
}

// ---------------- aggregation layer 3 (Dout=64) + fused log_softmax --------------
__global__ __launch_bounds__(256) void agg3_lsm_kernel(
    const ushort* __restrict__ xw, const int* __restrict__ cnt,
    const ushort* __restrict__ slots, const float* __restrict__ bias,
    float* __restrict__ e3, float* __restrict__ logp, int n) {
    const int tid = threadIdx.x;
    const int node = blockIdx.x * 32 + (tid >> 3);
    const int j = tid & 7;
    if (node >= n) return;
    const uint4* xw4 = (const uint4*)xw;   // row pitch = 8 uint4
    const int degf = cnt[node];
    const int deg = (degf < SLOT_CAP) ? degf : SLOT_CAP;
    const float di = rsqrtf((float)(degf + 1));
    const int base = node << 6;
    float acc[8];
#pragma unroll
    for (int i = 0; i < 8; ++i) acc[i] = 0.f;

    int p = 0;
    while (p + 8 <= deg) {
        const uint4 cw = *(const uint4*)&slots[base + p];
        const int s0 = cw.x & 0xffff, s1 = cw.x >> 16;
        const int s2 = cw.y & 0xffff, s3 = cw.y >> 16;
        const int s4 = cw.z & 0xffff, s5 = cw.z >> 16;
        const int s6 = cw.w & 0xffff, s7 = cw.w >> 16;
        uint4 v0 = xw4[(size_t)s0 * 8 + j];
        uint4 v1 = xw4[(size_t)s1 * 8 + j];
        uint4 v2 = xw4[(size_t)s2 * 8 + j];
        uint4 v3 = xw4[(size_t)s3 * 8 + j];
        uint4 v4 = xw4[(size_t)s4 * 8 + j];
        uint4 v5 = xw4[(size_t)s5 * 8 + j];
        uint4 v6 = xw4[(size_t)s6 * 8 + j];
        uint4 v7 = xw4[(size_t)s7 * 8 + j];
        ADD8(v0) ADD8(v1) ADD8(v2) ADD8(v3)
        ADD8(v4) ADD8(v5) ADD8(v6) ADD8(v7)
        p += 8;
    }
    if (p + 4 <= deg) {
        const uint2 cw = *(const uint2*)&slots[base + p];
        const int s0 = cw.x & 0xffff, s1 = cw.x >> 16;
        const int s2 = cw.y & 0xffff, s3 = cw.y >> 16;
        uint4 v0 = xw4[(size_t)s0 * 8 + j];
        uint4 v1 = xw4[(size_t)s1 * 8 + j];
        uint4 v2 = xw4[(size_t)s2 * 8 + j];
        uint4 v3 = xw4[(size_t)s3 * 8 + j];
        ADD8(v0) ADD8(v1) ADD8(v2) ADD8(v3)
        p += 4;
    }
    for (; p < deg; ++p) {
        const int s = slots[base + p];
        uint4 vv = xw4[(size_t)s * 8 + j];
        ADD8(vv)
    }
    uint4 vs = xw4[(size_t)node * 8 + j];
    acc[0] += bflo(vs.x); acc[1] += bfhi(vs.x);
    acc[2] += bflo(vs.y); acc[3] += bfhi(vs.y);
    acc[4] += bflo(vs.z); acc[5] += bfhi(vs.z);
    acc[6] += bflo(vs.w); acc[7] += bfhi(vs.w);
    const float4 blo = ((const float4*)bias)[2 * j];
    const float4 bhi = ((const float4*)bias)[2 * j + 1];
    const float bb[8] = { blo.x, blo.y, blo.z, blo.w, bhi.x, bhi.y, bhi.z, bhi.w };
    float o[8];
#pragma unroll
    for (int i = 0; i < 8; ++i) o[i] = di * acc[i] + bb[i];
    float* ep = e3 + (size_t)node * 64 + j * 8;
    ((float4*)ep)[0] = make_float4(o[0], o[1], o[2], o[3]);
    ((float4*)ep)[1] = make_float4(o[4], o[5], o[6], o[7]);
    // fused log_softmax over the 8-lane group
    float m = o[0];
#pragma unroll
    for (int i = 1; i < 8; ++i) m = fmaxf(m, o[i]);
#pragma unroll
    for (int off = 1; off < 8; off <<= 1) m = fmaxf(m, __shfl_xor(m, off, 64));
    float s = 0.f;
#pragma unroll
    for (int i = 0; i < 8; ++i) s += expf(o[i] - m);
#pragma unroll
    for (int off = 1; off < 8; off <<= 1) s += __shfl_xor(s, off, 64);
    const float ls = m + logf(s);
    float* lp = logp + (size_t)node * 64 + j * 8;
    ((float4*)lp)[0] = make_float4(o[0] - ls, o[1] - ls, o[2] - ls, o[3] - ls);
    ((float4*)lp)[1] = make_float4(o[4] - ls, o[5] - ls, o[6] - ls, o[7] - ls);
}

// ---------------- driver ----------------
extern "C" void kernel_launch(void* const* d_in, const int* in_sizes, int n_in,
                              void* d_out, int out_size, void* d_ws, size_t ws_size,
                              hipStream_t stream) {
    const float* x  = (const float*)d_in[0];
    const void*  ei = d_in[1];
    const float* W1 = (const float*)d_in[2];
    const float* b1 = (const float*)d_in[3];
    const float* W2 = (const float*)d_in[4];
    const float* b2 = (const float*)d_in[5];
    const float* W3 = (const float*)d_in[6];
    const float* b3 = (const float*)d_in[7];
    float* out = (float*)d_out;

    const int N = in_sizes[0] / 128;   // 50000
    const int E = in_sizes[1] / 2;     // 800000

    char* w = (char*)d_ws;
    size_t off = 0;
    auto alloc = [&](size_t bytes) -> void* {
        void* p = w + off;
        off = (off + bytes + 255) & ~(size_t)255;
        return p;
    };
    int*    cnt    = (int*)alloc((size_t)N * 4);
    ushort* slots  = (ushort*)alloc((size_t)N * SLOT_CAP * 2);  // 6.4 MB
    ushort* xw     = (ushort*)alloc((size_t)N * 128 * 2);       // bf16 GEMM output (dinv-scaled)
    ushort* xwb    = (ushort*)alloc((size_t)N * 128 * 2);       // bf16 relu'd agg output
    ushort* Wt1    = (ushort*)alloc(16384 * 2);
    ushort* Wt2    = (ushort*)alloc(16384 * 2);
    ushort* Wt3    = (ushort*)alloc(8192 * 2);

    float* logp = out;
    float* e1 = out + (size_t)N * 64;
    float* e2 = e1 + (size_t)N * 128;
    float* e3 = e2 + (size_t)N * 128;

    const int nper = (N + 7) / 8;                      // dst-partition width
    const int nch = (E + FILL_CHUNK - 1) / FILL_CHUNK; // edge chunks
    const int nfill = nch * 8;
    const int gblocks = (N + 127) / 128;

    hipMemsetAsync(cnt, 0, (size_t)N * 4, stream);
    fill_prep_kernel<<<nfill + 160, 256, 0, stream>>>(ei, E, nper, cnt, slots,
                                                      W1, W2, W3, Wt1, Wt2, Wt3, nfill);
    // layer 1
    mfma_gemm_f32_kernel<<<gblocks, 256, 0, stream>>>(x, Wt1, cnt, xw, N);
    agg12_kernel<<<(N + 15) / 16, 256, 0, stream>>>(xw, cnt, slots, b1, e1, xwb, N);
    // layer 2
    mfma_gemm_b_kernel<128><<<gblocks, 256, 0, stream>>>(xwb, Wt2, cnt, xw, N);
    agg12_kernel<<<(N + 15) / 16, 256, 0, stream>>>(xw, cnt, slots, b2, e2, xwb, N);
    // layer 3 (Dout=64) + log_softmax
    mfma_gemm_b_kernel<64><<<gblocks, 256, 0, stream>>>(xwb, Wt3, cnt, xw, N);
    agg3_lsm_kernel<<<(N + 31) / 32, 256, 0, stream>>>(xw, cnt, slots, b3, e3, logp, N);
}